// Round 6
// baseline (372.478 us; speedup 1.0000x reference)
//
#include <hip/hip_runtime.h>
#include <math.h>

#define DIM 256
#define NUM_HEADS 8
#define HEAD_DIM 32
#define QL 1024
#define KVL 4096
#define BATCH 4
#define NTAB 16129          // 127*127
#define LOG2E 1.4426950408889634f

typedef __attribute__((ext_vector_type(8))) short short8;       // MFMA A/B frag (8 bf16)
typedef __attribute__((ext_vector_type(4))) float floatx4;      // MFMA C/D frag
typedef __attribute__((ext_vector_type(4))) unsigned short ushort4v;

__device__ inline unsigned short f2bf(float x) {
    unsigned u = __builtin_bit_cast(unsigned, x);
    unsigned r = (u + 0x7FFFu + ((u >> 16) & 1u)) >> 16;
    return (unsigned short)r;
}
__device__ inline float bf2f(unsigned short h) {
    return __builtin_bit_cast(float, (unsigned)h << 16);
}
__device__ inline floatx4 mfma16(short8 a, short8 b, floatx4 c) {
    return __builtin_amdgcn_mfma_f32_16x16x32_bf16(a, b, c, 0, 0, 0);
}

// ---------------------------------------------------------------------------
// Splitter + bias-table transpose, one dispatch.  Bt is transposed per-head
// AND pre-scaled by log2(e) so the attn inner loop is v_fma + v_exp2.
// ---------------------------------------------------------------------------
__global__ __launch_bounds__(256) void split_all(
    const float* __restrict__ q, const float* __restrict__ kv,
    const float* __restrict__ Wq, const float* __restrict__ Wkv,
    const float* __restrict__ Wp, const float* __restrict__ bias_table,
    unsigned short* __restrict__ qh, unsigned short* __restrict__ kvh,
    unsigned short* __restrict__ Wqh, unsigned short* __restrict__ Wkvh,
    unsigned short* __restrict__ Wph, unsigned short* __restrict__ Wpl,
    float* __restrict__ Bt)
{
    const int gid = blockIdx.x * 256 + threadIdx.x;
    if (gid >= 1408514) return;
    if (gid >= 1376256) {                 // bias-table transpose region
        const int local = gid - 1376256;
        const float4 v = ((const float4*)bias_table)[local];
        const float vv[4] = {v.x, v.y, v.z, v.w};
        const int base = local * 4;
#pragma unroll
        for (int j = 0; j < 4; ++j) {
            const int i = (base + j) >> 3, h = (base + j) & 7;
            Bt[h * NTAB + i] = vv[j] * LOG2E;
        }
        return;
    }
    const float* src; unsigned short* dh; unsigned short* dl = nullptr; int local;
    if (gid < 262144)       { src = q;   dh = qh;   local = gid; }
    else if (gid < 1310720) { src = kv;  dh = kvh;  local = gid - 262144; }
    else if (gid < 1327104) { src = Wq;  dh = Wqh;  local = gid - 1310720; }
    else if (gid < 1359872) { src = Wkv; dh = Wkvh; local = gid - 1327104; }
    else                    { src = Wp;  dh = Wph;  dl = Wpl; local = gid - 1359872; }
    const float4 v = ((const float4*)src)[local];
    ushort4v h;
    h[0] = f2bf(v.x); h[1] = f2bf(v.y); h[2] = f2bf(v.z); h[3] = f2bf(v.w);
    ((ushort4v*)dh)[local] = h;
    if (dl) {
        ushort4v l;
        l[0] = f2bf(v.x - bf2f(h[0])); l[1] = f2bf(v.y - bf2f(h[1]));
        l[2] = f2bf(v.z - bf2f(h[2])); l[3] = f2bf(v.w - bf2f(h[3]));
        ((ushort4v*)dl)[local] = l;
    }
}

// ---------------------------------------------------------------------------
// LDS-free MFMA GEMM core with 2-stage k-pipeline. Wave tile = 32m x 64n,
// BW waves stacked in m. MODE 0: 3-pass hi/lo split, fp32 C.
// MODE 1: Qb  MODE 2: Kb  MODE 3: Vt (transposed store).
// ---------------------------------------------------------------------------
template<int MODE, int BW>
__device__ __forceinline__ void gemm_core(
    const unsigned short* __restrict__ Ah, const unsigned short* __restrict__ Al,
    const unsigned short* __restrict__ Wh, const unsigned short* __restrict__ Wl,
    const float* __restrict__ bias, float* __restrict__ Cf,
    unsigned short* __restrict__ Cb, float scale, int bx, int by)
{
    constexpr bool THREE = (MODE == 0);
    const int t    = threadIdx.x;
    const int w    = t >> 6;
    const int lane = t & 63;
    const int n16  = lane & 15;
    const int quad = lane >> 4;
    const int m0 = by * (BW * 32) + w * 32;
    const int n0 = bx * 64;

    floatx4 acc[2][4];
#pragma unroll
    for (int s = 0; s < 2; ++s)
#pragma unroll
        for (int c = 0; c < 4; ++c) acc[s][c] = (floatx4){0.f, 0.f, 0.f, 0.f};

    short8 af[2][2], afl[2][2], wf[2][4], wfl[2][4];

    auto LD = [&](int kb, int bi) {
#pragma unroll
        for (int s = 0; s < 2; ++s) {
            af[bi][s] = *(const short8*)(Ah + (size_t)(m0 + s * 16 + n16) * 256 + kb + quad * 8);
            if (THREE)
                afl[bi][s] = *(const short8*)(Al + (size_t)(m0 + s * 16 + n16) * 256 + kb + quad * 8);
        }
#pragma unroll
        for (int c = 0; c < 4; ++c) {
            wf[bi][c] = *(const short8*)(Wh + (size_t)(n0 + c * 16 + n16) * 256 + kb + quad * 8);
            if (THREE)
                wfl[bi][c] = *(const short8*)(Wl + (size_t)(n0 + c * 16 + n16) * 256 + kb + quad * 8);
        }
    };

    LD(0, 0);
#pragma unroll
    for (int i = 0; i < 8; ++i) {
        const int cur = i & 1, nxt = cur ^ 1;
        if (i < 7) LD((i + 1) * 32, nxt);
#pragma unroll
        for (int c = 0; c < 4; ++c)
#pragma unroll
            for (int s = 0; s < 2; ++s) {
                acc[s][c] = mfma16(af[cur][s], wf[cur][c], acc[s][c]);
                if (THREE) {
                    acc[s][c] = mfma16(af[cur][s], wfl[cur][c], acc[s][c]);
                    acc[s][c] = mfma16(afl[cur][s], wf[cur][c], acc[s][c]);
                }
            }
    }

#pragma unroll
    for (int s = 0; s < 2; ++s)
#pragma unroll
        for (int c = 0; c < 4; ++c) {
            const floatx4 v = acc[s][c];
            const int n_g = n0 + c * 16 + n16;
#pragma unroll
            for (int r = 0; r < 4; ++r) {
                const int m_g = m0 + s * 16 + quad * 4 + r;
                const float val = v[r];
                if (MODE == 0) {
                    Cf[(size_t)m_g * 256 + n_g] = val + bias[n_g];
                } else if (MODE == 1) {
                    const int h = n_g >> 5, d = n_g & 31;
                    const int b = m_g >> 10, qq = m_g & 1023;
                    Cb[(((size_t)(b * 8 + h) * 1024 + qq) << 5) + d] =
                        f2bf((val + bias[n_g]) * scale);
                } else if (MODE == 2) {
                    const int h = n_g >> 5, d = n_g & 31;
                    const int b = m_g >> 12, kvr = m_g & 4095;
                    Cb[(((size_t)(b * 8 + h) * 4096 + kvr) << 5) + d] =
                        f2bf(val + bias[n_g]);
                } else {
                    const int h = m_g >> 5, dd = m_g & 31;
                    const int b = n_g >> 12, kvr = n_g & 4095;
                    Cb[(((size_t)((b * 8 + h) * 32 + dd)) << 12) + kvr] =
                        f2bf(val + bias[m_g]);
                }
            }
        }
}

// Fused Q/K/V projections: blocks [0,128)=Q, [128,640)=K, [640,1152)=V.
__global__ __launch_bounds__(256) void gemm_qkv(
    const unsigned short* __restrict__ qh, const unsigned short* __restrict__ kvh,
    const unsigned short* __restrict__ Wqh, const unsigned short* __restrict__ Wkvh,
    const float* __restrict__ bq, const float* __restrict__ bkv,
    unsigned short* __restrict__ Qb, unsigned short* __restrict__ Kb,
    unsigned short* __restrict__ Vt, float scale)
{
    const int id = blockIdx.x;
    if (id < 128) {
        gemm_core<1, 4>(qh, nullptr, Wqh, nullptr, bq, nullptr, Qb, scale,
                        id & 3, id >> 2);                       // 4 n x 32 m
    } else if (id < 640) {
        const int t2 = id - 128;
        gemm_core<2, 4>(kvh, nullptr, Wkvh, nullptr, bkv, nullptr, Kb, 1.0f,
                        t2 & 3, t2 >> 2);                       // 4 n x 128 m
    } else {
        const int t2 = id - 640;
        gemm_core<3, 4>(Wkvh + 256 * 256, nullptr, kvh, nullptr, bkv + 256,
                        nullptr, Vt, 1.0f, t2 >> 1, t2 & 1);    // 256 n x 2 m
    }
}

// Out projection, 3-pass hi/lo split (fp32-grade accuracy).
__global__ __launch_bounds__(128) void gemm_out(
    const unsigned short* __restrict__ Xh, const unsigned short* __restrict__ Xl,
    const unsigned short* __restrict__ Wph, const unsigned short* __restrict__ Wpl,
    const float* __restrict__ bp, float* __restrict__ out)
{
    gemm_core<0, 2>(Xh, Xl, Wph, Wpl, bp, out, nullptr, 1.0f,
                    blockIdx.x, blockIdx.y);
}

// ---------------------------------------------------------------------------
// MFMA attention, XCD-swizzled + fully pipelined.
// Grid 2048 1-D: qt = id>>7 (HIGH bits!), rest = id&127 -> (b,sp,h).
// All 16 qt-blocks sharing a (b,h,sp) K/V slice have ids congruent mod 8 ->
// same XCD under round-robin dispatch -> each K/V slice fetched by one XCD
// only (per-XCD L2 working set ~2MB < 4MB).
// K-frags and bias gathers double-buffered one kt ahead (chain-critical).
// ---------------------------------------------------------------------------
__global__ __launch_bounds__(256, 3) void attn_mfma(
    const unsigned short* __restrict__ Qb,   // [32][1024][32] bf16, pre-scaled
    const unsigned short* __restrict__ Kb,   // [32][4096][32] bf16
    const unsigned short* __restrict__ Vt,   // [32][32][4096] bf16
    const float* __restrict__ Bt,            // [8][16129] fp32 (pre * log2e)
    float* __restrict__ Op,                  // [4][32][1024][32] fp32 unnormalized
    float* __restrict__ lp)                  // [4][32][1024]
{
    const int id   = blockIdx.x;
    const int qt   = id >> 7;
    const int rest = id & 127;
    const int h    = rest & 7;
    const int sp   = (rest >> 3) & 3;
    const int b    = rest >> 5;
    const int bh = b * NUM_HEADS + h;
    const int tid  = threadIdx.x;
    const int w    = tid >> 6;
    const int lane = tid & 63;
    const int n    = lane & 15;
    const int quad = lane >> 4;

    __shared__ __align__(16) unsigned short Ps[4][16 * 72];

    const int qrowA = qt * 64 + w * 16 + n;
    const short8 qf = *(const short8*)(Qb + (((size_t)bh * QL + qrowA) << 5) + quad * 8);

    const int qgC = qt * 64 + w * 16 + quad * 4;
    const float* Bth = Bt + h * NTAB;

    // kt-invariant pieces of the rel-index closed form (vS = sp>>1 const/block)
    const int vS = sp >> 1;
    int ivals[4];
    int M[4][4];
#pragma unroll
    for (int r = 0; r < 4; ++r) {
        const int q = qgC + r;
        ivals[r] = q >> 5;
        const int B0 = (((q & 31) << 1) + vS) << 5;
#pragma unroll
        for (int c = 0; c < 4; ++c) {
            const int bb = B0 + c * 16 + n;
            M[r][c] = (bb >> 6) * 127 + (bb & 63);
        }
    }

    floatx4 o0 = {0.f, 0.f, 0.f, 0.f};
    floatx4 o1 = {0.f, 0.f, 0.f, 0.f};
    float lacc[4] = {0.f, 0.f, 0.f, 0.f};

    const unsigned short* Kbase = Kb + (((size_t)bh * KVL) << 5);
    const unsigned short* Vbase = Vt + (((size_t)bh * 32) << 12);
    const int kbase = sp * 1024;

    short8 kf[2][4];
    float  bv[2][16];

    auto LDK = [&](int kt, int bi) {
        const int kv0 = kbase + kt * 64;
#pragma unroll
        for (int c = 0; c < 4; ++c)
            kf[bi][c] = *(const short8*)(Kbase + ((size_t)(kv0 + c * 16 + n) << 5) + quad * 8);
    };
    auto GATHER = [&](int kt, int bi) {
        const int jS = ((sp << 4) + kt) & 31;
#pragma unroll
        for (int r = 0; r < 4; ++r) {
            const int a  = 528 + (ivals[r] << 5) + jS;
            const int A0 = ((a >> 6) + 63) * 127 + (a & 63) + 63;
#pragma unroll
            for (int c = 0; c < 4; ++c)
                bv[bi][r * 4 + c] = Bth[A0 - M[r][c]];
        }
    };

    LDK(0, 0);
    GATHER(0, 0);

#pragma unroll 2
    for (int kt = 0; kt < 16; ++kt) {
        const int cur = kt & 1, nxt = cur ^ 1;
        const int kv0 = kbase + kt * 64;

        // V frags for this tile (consumed at iteration end -> latency covered)
        short8 vf[2][2];
#pragma unroll
        for (int kc = 0; kc < 2; ++kc)
#pragma unroll
            for (int dh = 0; dh < 2; ++dh)
                vf[kc][dh] = *(const short8*)(Vbase + ((size_t)(dh * 16 + n) << 12)
                                              + kv0 + kc * 32 + quad * 8);

        // S(16x64) = Q K^T
        floatx4 sc[4];
#pragma unroll
        for (int c = 0; c < 4; ++c) {
            floatx4 z = {0.f, 0.f, 0.f, 0.f};
            sc[c] = mfma16(qf, kf[cur][c], z);
        }

        // prefetch next K tile + next bias gather (full body to land)
        if (kt < 15) { LDK(kt + 1, nxt); GATHER(kt + 1, nxt); }

        // p = 2^(s*log2e + bias*log2e); accumulate l; P -> per-wave LDS
#pragma unroll
        for (int r = 0; r < 4; ++r)
#pragma unroll
            for (int c = 0; c < 4; ++c) {
                const float p = exp2f(fmaf(sc[c][r], LOG2E, bv[cur][r * 4 + c]));
                lacc[r] += p;
                Ps[w][(quad * 4 + r) * 72 + c * 16 + n] = f2bf(p);
            }
        // wave-internal LDS write->read ordering (Ps is per-wave)
        asm volatile("s_waitcnt lgkmcnt(0)" ::: "memory");

        // O(16x32) += P(16x64) V(64x32)
#pragma unroll
        for (int kc = 0; kc < 2; ++kc) {
            const short8 pf = *(const short8*)(Ps[w] + n * 72 + kc * 32 + quad * 8);
            o0 = mfma16(pf, vf[kc][0], o0);
            o1 = mfma16(pf, vf[kc][1], o1);
        }
        asm volatile("" ::: "memory");
    }

#pragma unroll
    for (int r = 0; r < 4; ++r) {
        float v = lacc[r];
        v += __shfl_xor(v, 1, 16);
        v += __shfl_xor(v, 2, 16);
        v += __shfl_xor(v, 4, 16);
        v += __shfl_xor(v, 8, 16);
        lacc[r] = v;
    }

    float* Opb = Op + (((size_t)(sp * 32 + bh) * QL) << 5);
#pragma unroll
    for (int r = 0; r < 4; ++r) {
        const int qg = qgC + r;
        Opb[((size_t)qg << 5) + n]      = o0[r];
        Opb[((size_t)qg << 5) + 16 + n] = o1[r];
    }
    if (n == 0) {
        float* lpb = lp + (size_t)(sp * 32 + bh) * QL;
#pragma unroll
        for (int r = 0; r < 4; ++r) lpb[qgC + r] = lacc[r];
    }
}

// ---------------------------------------------------------------------------
// Combine kv-splits and emit X directly as bf16 hi/lo for the 3-pass out-proj.
// ---------------------------------------------------------------------------
__global__ __launch_bounds__(256) void attn_combine(
    const float* __restrict__ Op, const float* __restrict__ lp,
    unsigned short* __restrict__ Xh, unsigned short* __restrict__ Xl)
{
    const int gid = blockIdx.x * 256 + threadIdx.x;     // 0 .. 2^20-1
    const int bhq = gid >> 5, d = gid & 31;
    const int bh = bhq >> 10, q = bhq & 1023;
    const int b = bh >> 3, hh = bh & 7;
    float o = 0.f, l = 0.f;
#pragma unroll
    for (int s = 0; s < 4; ++s) {
        o += Op[((size_t)(s * 32768 + bhq) << 5) + d];
        l += lp[s * 32768 + bhq];
    }
    const float val = o / l;
    const size_t idx = ((size_t)(b * QL + q)) * DIM + hh * HEAD_DIM + d;
    const unsigned short h = f2bf(val);
    Xh[idx] = h;
    Xl[idx] = f2bf(val - bf2f(h));
}

// ---------------------------------------------------------------------------
extern "C" void kernel_launch(void* const* d_in, const int* in_sizes, int n_in,
                              void* d_out, int out_size, void* d_ws, size_t ws_size,
                              hipStream_t stream)
{
    const float* q          = (const float*)d_in[0];
    const float* kv         = (const float*)d_in[1];
    const float* Wq         = (const float*)d_in[2];
    const float* bq         = (const float*)d_in[3];
    const float* Wkv        = (const float*)d_in[4];
    const float* bkv        = (const float*)d_in[5];
    const float* bias_table = (const float*)d_in[6];
    const float* Wp         = (const float*)d_in[7];
    const float* bp         = (const float*)d_in[8];
    float* out = (float*)d_out;

    // Workspace map (38.63 MB; aliases safe by stream order):
    //  [ 0, 2M)   Qb          [ 2M,10M)  Kb          [10M,18M)  Vt (Xl aliases)
    //  [18M,34M)  kvh (dead after QKV gemms) / Op    [34M,34.5M) lp
    //  [34.5M,35.03M) Bt      [36M,38M)  qh (Xh aliases)   [38M,38.63M) W splits
    char* ws = (char*)d_ws;
    unsigned short* Qb   = (unsigned short*)(ws);
    unsigned short* Kb   = (unsigned short*)(ws + (size_t)(2u  << 20));
    unsigned short* Vt   = (unsigned short*)(ws + (size_t)(10u << 20));
    unsigned short* kvh  = (unsigned short*)(ws + (size_t)(18u << 20));
    float*          Op   = (float*)         (ws + (size_t)(18u << 20));
    float*          lp   = (float*)         (ws + (size_t)(34u << 20));
    float*          Bt   = (float*)         (ws + (size_t)(34u << 20) + (512u << 10));
    unsigned short* qh   = (unsigned short*)(ws + (size_t)(36u << 20));
    unsigned short* Wqh  = (unsigned short*)(ws + (size_t)(38u << 20));
    unsigned short* Wkvh = (unsigned short*)(ws + (size_t)(38u << 20) + (128u << 10));
    unsigned short* Wph  = (unsigned short*)(ws + (size_t)(38u << 20) + (384u << 10));
    unsigned short* Wpl  = (unsigned short*)(ws + (size_t)(38u << 20) + (512u << 10));
    unsigned short* Xh   = qh;               // alias: qh dead after QKV gemms
    unsigned short* Xl   = Vt;               // alias: Vt dead after attention

    const float scale = 1.0f / sqrtf((float)HEAD_DIM);

    split_all<<<dim3(5503), 256, 0, stream>>>(q, kv, Wq, Wkv, Wp, bias_table,
                                              qh, kvh, Wqh, Wkvh, Wph, Wpl, Bt);
    // Q + K + V projections, one dispatch
    gemm_qkv<<<dim3(1152), 256, 0, stream>>>(qh, kvh, Wqh, Wkvh, bq, bkv,
                                             Qb, Kb, Vt, scale);
    // fused attention (XCD-swizzled 1-D grid)
    attn_mfma<<<dim3(2048), 256, 0, stream>>>(Qb, Kb, Vt, Bt, Op, lp);
    // combine kv-splits -> X (hi/lo bf16)
    attn_combine<<<dim3(4096), 256, 0, stream>>>(Op, lp, Xh, Xl);
    // out projection, 3-pass split bf16 (~fp32 accuracy)
    gemm_out<<<dim3(4, 64), 128, 0, stream>>>(Xh, Xl, Wph, Wpl, bp, out);
}

// Round 7
// 246.117 us; speedup vs baseline: 1.5134x; 1.5134x over previous
//
#include <hip/hip_runtime.h>
#include <math.h>

#define DIM 256
#define NUM_HEADS 8
#define HEAD_DIM 32
#define QL 1024
#define KVL 4096
#define BATCH 4
#define NTAB 16129          // 127*127
#define LOG2E 1.4426950408889634f

typedef __attribute__((ext_vector_type(8))) short short8;       // MFMA A/B frag (8 bf16)
typedef __attribute__((ext_vector_type(4))) float floatx4;      // MFMA C/D frag
typedef __attribute__((ext_vector_type(4))) unsigned short ushort4v;

__device__ inline unsigned short f2bf(float x) {
    unsigned u = __builtin_bit_cast(unsigned, x);
    unsigned r = (u + 0x7FFFu + ((u >> 16) & 1u)) >> 16;
    return (unsigned short)r;
}
__device__ inline float bf2f(unsigned short h) {
    return __builtin_bit_cast(float, (unsigned)h << 16);
}
__device__ inline floatx4 mfma16(short8 a, short8 b, floatx4 c) {
    return __builtin_amdgcn_mfma_f32_16x16x32_bf16(a, b, c, 0, 0, 0);
}

// ---------------------------------------------------------------------------
// Splitter + bias-table transpose, one dispatch.  Bt is transposed per-head
// AND pre-scaled by log2(e) so the attn inner loop is v_fma + v_exp2.
// ---------------------------------------------------------------------------
__global__ __launch_bounds__(256) void split_all(
    const float* __restrict__ q, const float* __restrict__ kv,
    const float* __restrict__ Wq, const float* __restrict__ Wkv,
    const float* __restrict__ Wp, const float* __restrict__ bias_table,
    unsigned short* __restrict__ qh, unsigned short* __restrict__ kvh,
    unsigned short* __restrict__ Wqh, unsigned short* __restrict__ Wkvh,
    unsigned short* __restrict__ Wph, unsigned short* __restrict__ Wpl,
    float* __restrict__ Bt)
{
    const int gid = blockIdx.x * 256 + threadIdx.x;
    if (gid >= 1408514) return;
    if (gid >= 1376256) {                 // bias-table transpose region
        const int local = gid - 1376256;
        const float4 v = ((const float4*)bias_table)[local];
        const float vv[4] = {v.x, v.y, v.z, v.w};
        const int base = local * 4;
#pragma unroll
        for (int j = 0; j < 4; ++j) {
            const int i = (base + j) >> 3, h = (base + j) & 7;
            Bt[h * NTAB + i] = vv[j] * LOG2E;
        }
        return;
    }
    const float* src; unsigned short* dh; unsigned short* dl = nullptr; int local;
    if (gid < 262144)       { src = q;   dh = qh;   local = gid; }
    else if (gid < 1310720) { src = kv;  dh = kvh;  local = gid - 262144; }
    else if (gid < 1327104) { src = Wq;  dh = Wqh;  local = gid - 1310720; }
    else if (gid < 1359872) { src = Wkv; dh = Wkvh; local = gid - 1327104; }
    else                    { src = Wp;  dh = Wph;  dl = Wpl; local = gid - 1359872; }
    const float4 v = ((const float4*)src)[local];
    ushort4v h;
    h[0] = f2bf(v.x); h[1] = f2bf(v.y); h[2] = f2bf(v.z); h[3] = f2bf(v.w);
    ((ushort4v*)dh)[local] = h;
    if (dl) {
        ushort4v l;
        l[0] = f2bf(v.x - bf2f(h[0])); l[1] = f2bf(v.y - bf2f(h[1]));
        l[2] = f2bf(v.z - bf2f(h[2])); l[3] = f2bf(v.w - bf2f(h[3]));
        ((ushort4v*)dl)[local] = l;
    }
}

// ---------------------------------------------------------------------------
// LDS-free MFMA GEMM core with 2-stage k-pipeline. Wave tile = 32m x 64n,
// BW waves stacked in m. MODE 0: 3-pass hi/lo split, fp32 C.
// MODE 1: Qb  MODE 2: Kb  MODE 3: Vt (transposed store).
// ---------------------------------------------------------------------------
template<int MODE, int BW>
__device__ __forceinline__ void gemm_core(
    const unsigned short* __restrict__ Ah, const unsigned short* __restrict__ Al,
    const unsigned short* __restrict__ Wh, const unsigned short* __restrict__ Wl,
    const float* __restrict__ bias, float* __restrict__ Cf,
    unsigned short* __restrict__ Cb, float scale, int bx, int by)
{
    constexpr bool THREE = (MODE == 0);
    const int t    = threadIdx.x;
    const int w    = t >> 6;
    const int lane = t & 63;
    const int n16  = lane & 15;
    const int quad = lane >> 4;
    const int m0 = by * (BW * 32) + w * 32;
    const int n0 = bx * 64;

    floatx4 acc[2][4];
#pragma unroll
    for (int s = 0; s < 2; ++s)
#pragma unroll
        for (int c = 0; c < 4; ++c) acc[s][c] = (floatx4){0.f, 0.f, 0.f, 0.f};

    short8 af[2][2], afl[2][2], wf[2][4], wfl[2][4];

    auto LD = [&](int kb, int bi) {
#pragma unroll
        for (int s = 0; s < 2; ++s) {
            af[bi][s] = *(const short8*)(Ah + (size_t)(m0 + s * 16 + n16) * 256 + kb + quad * 8);
            if (THREE)
                afl[bi][s] = *(const short8*)(Al + (size_t)(m0 + s * 16 + n16) * 256 + kb + quad * 8);
        }
#pragma unroll
        for (int c = 0; c < 4; ++c) {
            wf[bi][c] = *(const short8*)(Wh + (size_t)(n0 + c * 16 + n16) * 256 + kb + quad * 8);
            if (THREE)
                wfl[bi][c] = *(const short8*)(Wl + (size_t)(n0 + c * 16 + n16) * 256 + kb + quad * 8);
        }
    };

    LD(0, 0);
#pragma unroll
    for (int i = 0; i < 8; ++i) {
        const int cur = i & 1, nxt = cur ^ 1;
        if (i < 7) LD((i + 1) * 32, nxt);
#pragma unroll
        for (int c = 0; c < 4; ++c)
#pragma unroll
            for (int s = 0; s < 2; ++s) {
                acc[s][c] = mfma16(af[cur][s], wf[cur][c], acc[s][c]);
                if (THREE) {
                    acc[s][c] = mfma16(af[cur][s], wfl[cur][c], acc[s][c]);
                    acc[s][c] = mfma16(afl[cur][s], wf[cur][c], acc[s][c]);
                }
            }
    }

#pragma unroll
    for (int s = 0; s < 2; ++s)
#pragma unroll
        for (int c = 0; c < 4; ++c) {
            const floatx4 v = acc[s][c];
            const int n_g = n0 + c * 16 + n16;
#pragma unroll
            for (int r = 0; r < 4; ++r) {
                const int m_g = m0 + s * 16 + quad * 4 + r;
                const float val = v[r];
                if (MODE == 0) {
                    Cf[(size_t)m_g * 256 + n_g] = val + bias[n_g];
                } else if (MODE == 1) {
                    const int h = n_g >> 5, d = n_g & 31;
                    const int b = m_g >> 10, qq = m_g & 1023;
                    Cb[(((size_t)(b * 8 + h) * 1024 + qq) << 5) + d] =
                        f2bf((val + bias[n_g]) * scale);
                } else if (MODE == 2) {
                    const int h = n_g >> 5, d = n_g & 31;
                    const int b = m_g >> 12, kvr = m_g & 4095;
                    Cb[(((size_t)(b * 8 + h) * 4096 + kvr) << 5) + d] =
                        f2bf(val + bias[n_g]);
                } else {
                    const int h = m_g >> 5, dd = m_g & 31;
                    const int b = n_g >> 12, kvr = n_g & 4095;
                    Cb[(((size_t)((b * 8 + h) * 32 + dd)) << 12) + kvr] =
                        f2bf(val + bias[m_g]);
                }
            }
        }
}

// Fused Q/K/V projections: blocks [0,128)=Q, [128,640)=K, [640,1152)=V.
__global__ __launch_bounds__(256) void gemm_qkv(
    const unsigned short* __restrict__ qh, const unsigned short* __restrict__ kvh,
    const unsigned short* __restrict__ Wqh, const unsigned short* __restrict__ Wkvh,
    const float* __restrict__ bq, const float* __restrict__ bkv,
    unsigned short* __restrict__ Qb, unsigned short* __restrict__ Kb,
    unsigned short* __restrict__ Vt, float scale)
{
    const int id = blockIdx.x;
    if (id < 128) {
        gemm_core<1, 4>(qh, nullptr, Wqh, nullptr, bq, nullptr, Qb, scale,
                        id & 3, id >> 2);                       // 4 n x 32 m
    } else if (id < 640) {
        const int t2 = id - 128;
        gemm_core<2, 4>(kvh, nullptr, Wkvh, nullptr, bkv, nullptr, Kb, 1.0f,
                        t2 & 3, t2 >> 2);                       // 4 n x 128 m
    } else {
        const int t2 = id - 640;
        gemm_core<3, 4>(Wkvh + 256 * 256, nullptr, kvh, nullptr, bkv + 256,
                        nullptr, Vt, 1.0f, t2 >> 1, t2 & 1);    // 256 n x 2 m
    }
}

// Out projection, 3-pass hi/lo split (fp32-grade accuracy).
__global__ __launch_bounds__(128) void gemm_out(
    const unsigned short* __restrict__ Xh, const unsigned short* __restrict__ Xl,
    const unsigned short* __restrict__ Wph, const unsigned short* __restrict__ Wpl,
    const float* __restrict__ bp, float* __restrict__ out)
{
    gemm_core<0, 2>(Xh, Xl, Wph, Wpl, bp, out, nullptr, 1.0f,
                    blockIdx.x, blockIdx.y);
}

// ---------------------------------------------------------------------------
// MFMA attention. XCD-swizzled 1-D grid, FULLY UNROLLED kt loop (all local
// array indices compile-time -> registers; round 6's partial unroll demoted
// kf/bv to scratch = 539MB spill traffic).
// Grid 2048: qt = id>>7 (high bits), so the 16 blocks sharing a (b,h,sp)
// K/V slice are congruent mod 8 -> same XCD -> slice L2-resident (~2MB/XCD).
// K-frags + bias gathers double-buffered one kt ahead.
// ---------------------------------------------------------------------------
__global__ __launch_bounds__(256, 3) void attn_mfma(
    const unsigned short* __restrict__ Qb,   // [32][1024][32] bf16, pre-scaled
    const unsigned short* __restrict__ Kb,   // [32][4096][32] bf16
    const unsigned short* __restrict__ Vt,   // [32][32][4096] bf16
    const float* __restrict__ Bt,            // [8][16129] fp32 (pre * log2e)
    float* __restrict__ Op,                  // [4][32][1024][32] fp32 unnormalized
    float* __restrict__ lp)                  // [4][32][1024]
{
    const int id   = blockIdx.x;
    const int qt   = id >> 7;
    const int rest = id & 127;
    const int h    = rest & 7;
    const int sp   = (rest >> 3) & 3;
    const int b    = rest >> 5;
    const int bh = b * NUM_HEADS + h;
    const int tid  = threadIdx.x;
    const int w    = tid >> 6;
    const int lane = tid & 63;
    const int n    = lane & 15;
    const int quad = lane >> 4;

    __shared__ __align__(16) unsigned short Ps[4][16 * 72];

    const int qrowA = qt * 64 + w * 16 + n;
    const short8 qf = *(const short8*)(Qb + (((size_t)bh * QL + qrowA) << 5) + quad * 8);

    const int qgC = qt * 64 + w * 16 + quad * 4;
    const float* Bth = Bt + h * NTAB;

    // kt-invariant pieces of the rel-index closed form (vS = sp>>1 const/block)
    const int vS = sp >> 1;
    int ivals[4], B0r[4];
#pragma unroll
    for (int r = 0; r < 4; ++r) {
        const int q = qgC + r;
        ivals[r] = q >> 5;
        B0r[r]   = (((q & 31) << 1) + vS) << 5;
    }

    floatx4 o0 = {0.f, 0.f, 0.f, 0.f};
    floatx4 o1 = {0.f, 0.f, 0.f, 0.f};
    float lacc[4] = {0.f, 0.f, 0.f, 0.f};

    const unsigned short* Kbase = Kb + (((size_t)bh * KVL) << 5);
    const unsigned short* Vbase = Vt + (((size_t)bh * 32) << 12);
    const int kbase = sp * 1024;

    short8 kf[2][4];
    float  bv[2][16];

    auto LDK = [&](int kt, int bi) {
        const int kv0 = kbase + kt * 64;
#pragma unroll
        for (int c = 0; c < 4; ++c)
            kf[bi][c] = *(const short8*)(Kbase + ((size_t)(kv0 + c * 16 + n) << 5) + quad * 8);
    };
    auto GATHER = [&](int kt, int bi) {
        const int jS = ((sp << 4) + kt) & 31;
#pragma unroll
        for (int r = 0; r < 4; ++r) {
            const int a  = 528 + (ivals[r] << 5) + jS;
            const int A0 = ((a >> 6) + 63) * 127 + (a & 63) + 63;
#pragma unroll
            for (int c = 0; c < 4; ++c) {
                const int bb  = B0r[r] + c * 16 + n;
                const int idx = A0 - ((bb >> 6) * 127 + (bb & 63));
                bv[bi][r * 4 + c] = Bth[idx];
            }
        }
    };

    LDK(0, 0);
    GATHER(0, 0);

#pragma unroll
    for (int kt = 0; kt < 16; ++kt) {
        const int cur = kt & 1, nxt = cur ^ 1;
        const int kv0 = kbase + kt * 64;

        // V frags for this tile (consumed at iteration end -> latency covered)
        short8 vf[2][2];
#pragma unroll
        for (int kc = 0; kc < 2; ++kc)
#pragma unroll
            for (int dh = 0; dh < 2; ++dh)
                vf[kc][dh] = *(const short8*)(Vbase + ((size_t)(dh * 16 + n) << 12)
                                              + kv0 + kc * 32 + quad * 8);

        // S(16x64) = Q K^T
        floatx4 sc[4];
#pragma unroll
        for (int c = 0; c < 4; ++c) {
            floatx4 z = {0.f, 0.f, 0.f, 0.f};
            sc[c] = mfma16(qf, kf[cur][c], z);
        }

        // prefetch next K tile + next bias gather (a full body to land)
        if (kt < 15) { LDK(kt + 1, nxt); GATHER(kt + 1, nxt); }

        // p = 2^(s*log2e + bias*log2e); accumulate l; P -> per-wave LDS
#pragma unroll
        for (int r = 0; r < 4; ++r)
#pragma unroll
            for (int c = 0; c < 4; ++c) {
                const float p = exp2f(fmaf(sc[c][r], LOG2E, bv[cur][r * 4 + c]));
                lacc[r] += p;
                Ps[w][(quad * 4 + r) * 72 + c * 16 + n] = f2bf(p);
            }
        // wave-internal LDS write->read ordering (Ps is per-wave)
        asm volatile("s_waitcnt lgkmcnt(0)" ::: "memory");

        // O(16x32) += P(16x64) V(64x32)
#pragma unroll
        for (int kc = 0; kc < 2; ++kc) {
            const short8 pf = *(const short8*)(Ps[w] + n * 72 + kc * 32 + quad * 8);
            o0 = mfma16(pf, vf[kc][0], o0);
            o1 = mfma16(pf, vf[kc][1], o1);
        }
        asm volatile("" ::: "memory");
    }

#pragma unroll
    for (int r = 0; r < 4; ++r) {
        float v = lacc[r];
        v += __shfl_xor(v, 1, 16);
        v += __shfl_xor(v, 2, 16);
        v += __shfl_xor(v, 4, 16);
        v += __shfl_xor(v, 8, 16);
        lacc[r] = v;
    }

    float* Opb = Op + (((size_t)(sp * 32 + bh) * QL) << 5);
#pragma unroll
    for (int r = 0; r < 4; ++r) {
        const int qg = qgC + r;
        Opb[((size_t)qg << 5) + n]      = o0[r];
        Opb[((size_t)qg << 5) + 16 + n] = o1[r];
    }
    if (n == 0) {
        float* lpb = lp + (size_t)(sp * 32 + bh) * QL;
#pragma unroll
        for (int r = 0; r < 4; ++r) lpb[qgC + r] = lacc[r];
    }
}

// ---------------------------------------------------------------------------
// Combine kv-splits and emit X directly as bf16 hi/lo for the 3-pass out-proj.
// ---------------------------------------------------------------------------
__global__ __launch_bounds__(256) void attn_combine(
    const float* __restrict__ Op, const float* __restrict__ lp,
    unsigned short* __restrict__ Xh, unsigned short* __restrict__ Xl)
{
    const int gid = blockIdx.x * 256 + threadIdx.x;     // 0 .. 2^20-1
    const int bhq = gid >> 5, d = gid & 31;
    const int bh = bhq >> 10, q = bhq & 1023;
    const int b = bh >> 3, hh = bh & 7;
    float o = 0.f, l = 0.f;
#pragma unroll
    for (int s = 0; s < 4; ++s) {
        o += Op[((size_t)(s * 32768 + bhq) << 5) + d];
        l += lp[s * 32768 + bhq];
    }
    const float val = o / l;
    const size_t idx = ((size_t)(b * QL + q)) * DIM + hh * HEAD_DIM + d;
    const unsigned short h = f2bf(val);
    Xh[idx] = h;
    Xl[idx] = f2bf(val - bf2f(h));
}

// ---------------------------------------------------------------------------
extern "C" void kernel_launch(void* const* d_in, const int* in_sizes, int n_in,
                              void* d_out, int out_size, void* d_ws, size_t ws_size,
                              hipStream_t stream)
{
    const float* q          = (const float*)d_in[0];
    const float* kv         = (const float*)d_in[1];
    const float* Wq         = (const float*)d_in[2];
    const float* bq         = (const float*)d_in[3];
    const float* Wkv        = (const float*)d_in[4];
    const float* bkv        = (const float*)d_in[5];
    const float* bias_table = (const float*)d_in[6];
    const float* Wp         = (const float*)d_in[7];
    const float* bp         = (const float*)d_in[8];
    float* out = (float*)d_out;

    // Workspace map (38.63 MB; aliases safe by stream order):
    //  [ 0, 2M)   Qb          [ 2M,10M)  Kb          [10M,18M)  Vt (Xl aliases)
    //  [18M,34M)  kvh (dead after QKV gemms) / Op    [34M,34.5M) lp
    //  [34.5M,35.03M) Bt      [36M,38M)  qh (Xh aliases)   [38M,38.63M) W splits
    char* ws = (char*)d_ws;
    unsigned short* Qb   = (unsigned short*)(ws);
    unsigned short* Kb   = (unsigned short*)(ws + (size_t)(2u  << 20));
    unsigned short* Vt   = (unsigned short*)(ws + (size_t)(10u << 20));
    unsigned short* kvh  = (unsigned short*)(ws + (size_t)(18u << 20));
    float*          Op   = (float*)         (ws + (size_t)(18u << 20));
    float*          lp   = (float*)         (ws + (size_t)(34u << 20));
    float*          Bt   = (float*)         (ws + (size_t)(34u << 20) + (512u << 10));
    unsigned short* qh   = (unsigned short*)(ws + (size_t)(36u << 20));
    unsigned short* Wqh  = (unsigned short*)(ws + (size_t)(38u << 20));
    unsigned short* Wkvh = (unsigned short*)(ws + (size_t)(38u << 20) + (128u << 10));
    unsigned short* Wph  = (unsigned short*)(ws + (size_t)(38u << 20) + (384u << 10));
    unsigned short* Wpl  = (unsigned short*)(ws + (size_t)(38u << 20) + (512u << 10));
    unsigned short* Xh   = qh;               // alias: qh dead after QKV gemms
    unsigned short* Xl   = Vt;               // alias: Vt dead after attention

    const float scale = 1.0f / sqrtf((float)HEAD_DIM);

    split_all<<<dim3(5503), 256, 0, stream>>>(q, kv, Wq, Wkv, Wp, bias_table,
                                              qh, kvh, Wqh, Wkvh, Wph, Wpl, Bt);
    // Q + K + V projections, one dispatch
    gemm_qkv<<<dim3(1152), 256, 0, stream>>>(qh, kvh, Wqh, Wkvh, bq, bkv,
                                             Qb, Kb, Vt, scale);
    // fused attention (XCD-swizzled 1-D grid)
    attn_mfma<<<dim3(2048), 256, 0, stream>>>(Qb, Kb, Vt, Bt, Op, lp);
    // combine kv-splits -> X (hi/lo bf16)
    attn_combine<<<dim3(4096), 256, 0, stream>>>(Op, lp, Xh, Xl);
    // out projection, 3-pass split bf16 (~fp32 accuracy)
    gemm_out<<<dim3(4, 64), 128, 0, stream>>>(Xh, Xl, Wph, Wpl, bp, out);
}